// Round 1
// 469.376 us; speedup vs baseline: 1.1334x; 1.1334x over previous
//
#include <hip/hip_runtime.h>

// Voxelizer: f32 pointclouds [4,200000,3] -> f32 occupancy grid [4,50,800,800].
// SEMANTICS (pinned by probe rounds 8-11 of the previous session):
//   bin = clip(floor(RN_f32(s * 5.0f)), 0, max)   [XLA: /0.2 -> *5.0, exact]
//   sx = x + 80.0f; sy = 80.0f - y; sz = z  (f32 adds, exact under any flags)
//   mask: x,y in [-80,80] (z only clamped); masked points are no-ops.
// Output values are only 0.0/1.0 -> scatter is an idempotent 1.0f store, no
// atomics.
//
// Timing budget (rocprof, this session):
//   ~342 us  harness poison fill, 2.048 GB @ ~6.0 TB/s   [fixed, untouchable]
//   ~88 us   harness d_out 0xAA poison, 512 MB           [fixed, untouchable]
//   ~95 us   our zero-fill (512 MB)  -> target ~86 us (6 TB/s write stream)
//   ~5 us    scatter (9.6 MB read + ~2 MB scattered stores)
// Change vs prev round: zero-fill was 500K wgs x 1 float4/thread (4 KB/wg,
// dispatch-overhead-bound). Now 2048 wgs x 256 thr grid-stride (64 stores per
// thread, full 32-wave/CU occupancy at 8 VGPR) to match rocclr fill's BW.

#define DD 50
#define HH 800
#define WW 800

__global__ __launch_bounds__(256) void zero_fill_kernel(float4* __restrict__ out4,
                                                        long long n4) {
    const long long stride = (long long)gridDim.x * blockDim.x;
    long long i = (long long)blockIdx.x * blockDim.x + threadIdx.x;
    const float4 z = make_float4(0.f, 0.f, 0.f, 0.f);
    // n4 = 32M, stride = 524288 -> exactly 64 iterations, no tail divergence.
    #pragma unroll 4
    for (; i < n4; i += stride) out4[i] = z;
}

__global__ __launch_bounds__(256) void voxelize_kernel(
        const float* __restrict__ pts,   // f32 [B*N*3]
        float* __restrict__ out,         // f32 [B*D*H*W]
        int N, int total) {
    int i = blockIdx.x * blockDim.x + threadIdx.x;
    if (i >= total) return;

    float x = pts[3 * i + 0];
    float y = pts[3 * i + 1];
    float z = pts[3 * i + 2];

    bool ok = (x >= -80.0f) & (x <= 80.0f) & (y >= -80.0f) & (y <= 80.0f);
    if (!ok) return;

    // keep the exact op sequence add -> mul -> floor (matches XLA's f32 math).
    int bx = (int)floorf((x + 80.0f) * 5.0f);
    int by = (int)floorf((80.0f - y) * 5.0f);
    int bz = (int)floorf(z * 5.0f);

    bx = min(max(bx, 0), WW - 1);
    by = min(max(by, 0), HH - 1);
    bz = min(max(bz, 0), DD - 1);

    int b = i / N;
    long long idx = (((long long)b * DD + bz) * HH + by) * WW + bx;
    out[idx] = 1.0f;   // idempotent: every writer stores the same value
}

extern "C" void kernel_launch(void* const* d_in, const int* in_sizes, int n_in,
                              void* d_out, int out_size, void* d_ws, size_t ws_size,
                              hipStream_t stream) {
    const float* pts = (const float*)d_in[0];
    float* out = (float*)d_out;

    const int B = 4;
    const int N = in_sizes[0] / (B * 3);   // 200000
    const int total = B * N;

    // 1) zero the grid: 128M f32 = 32M float4. Grid-stride, 2048 wgs:
    //    8 wgs/CU x 256 CUs, 64 float4 stores per thread.
    long long n4 = (long long)out_size / 16;
    zero_fill_kernel<<<2048, 256, 0, stream>>>((float4*)out, n4);

    // 2) scatter points.
    int blocks = (total + 255) / 256;
    voxelize_kernel<<<blocks, 256, 0, stream>>>(pts, out, N, total);
}